// Round 1
// baseline (1732.916 us; speedup 1.0000x reference)
//
#include <hip/hip_runtime.h>
#include <math.h>

#define B_ 8
#define C_ 64
#define H_ 128
#define W_ 128
#define HW_ (H_*W_)

// ---------------------------------------------------------------------------
// Direct 3x3 conv, pad=1, stride=1, NCHW. Tile 32x8 pixels, CO_BLK output
// channels per block. Weights read via block-uniform indices -> scalar loads.
// ---------------------------------------------------------------------------
template<int CIN, int COUT, int CO_BLK, bool RELU>
__global__ __launch_bounds__(256)
void conv3x3_k(const float* __restrict__ in, const float* __restrict__ w,
               float* __restrict__ out)
{
    constexpr int TW = 32, TH = 8;
    __shared__ float tile[TH+2][TW+2];
    const int tid = threadIdx.x;
    const int tx = tid & (TW-1);
    const int ty = tid / TW;
    const int tw = blockIdx.x & 3;        // W_/TW = 4
    const int th = blockIdx.x >> 2;       // H_/TH = 16
    const int co0 = blockIdx.y * CO_BLK;
    const int b  = blockIdx.z;
    const int w0 = tw*TW, h0 = th*TH;

    float acc[CO_BLK];
#pragma unroll
    for (int j=0;j<CO_BLK;j++) acc[j] = 0.f;

    const float* inb = in + (size_t)b*CIN*HW_;
    for (int ci=0; ci<CIN; ++ci){
        __syncthreads();
        const float* inc = inb + (size_t)ci*HW_;
        for (int idx=tid; idx<(TH+2)*(TW+2); idx+=256){
            const int r = idx/(TW+2), c = idx - r*(TW+2);
            const int iy = h0-1+r, ix = w0-1+c;
            float v = 0.f;
            if (iy>=0 && iy<H_ && ix>=0 && ix<W_) v = inc[iy*W_+ix];
            tile[r][c] = v;
        }
        __syncthreads();
        float xv[9];
#pragma unroll
        for (int r=0;r<3;r++)
#pragma unroll
            for (int s=0;s<3;s++)
                xv[r*3+s] = tile[ty+r][tx+s];
        const float* wci = w + ((size_t)co0*CIN + ci)*9;
#pragma unroll
        for (int j=0;j<CO_BLK;j++){
            const float* wp = wci + (size_t)j*CIN*9;   // block-uniform -> s_load
#pragma unroll
            for (int k=0;k<9;k++)
                acc[j] = fmaf(xv[k], wp[k], acc[j]);
        }
    }
    const int oh = h0+ty, ow = w0+tx;
#pragma unroll
    for (int j=0;j<CO_BLK;j++){
        float v = acc[j];
        if (RELU) v = fmaxf(v, 0.f);
        out[(((size_t)b*COUT + (co0+j))*H_ + oh)*W_ + ow] = v;
    }
}

// ---------------------------------------------------------------------------
// Bilinear gather matching the reference exactly (per-corner validity mask,
// clipped indices).
// ---------------------------------------------------------------------------
__device__ __forceinline__ float bilin(const float* __restrict__ xc,
                                       float py, float px)
{
    const float y0f = floorf(py), x0f = floorf(px);
    const float ay = py - y0f, ax = px - x0f;
    const int y0 = (int)y0f, x0 = (int)x0f;
    const int y1 = y0 + 1,   x1 = x0 + 1;
    const float my0 = (y0 >= 0 && y0 < H_) ? 1.f : 0.f;
    const float my1 = (y1 >= 0 && y1 < H_) ? 1.f : 0.f;
    const float mx0 = (x0 >= 0 && x0 < W_) ? 1.f : 0.f;
    const float mx1 = (x1 >= 0 && x1 < W_) ? 1.f : 0.f;
    const int y0c = min(max(y0,0),H_-1), y1c = min(max(y1,0),H_-1);
    const int x0c = min(max(x0,0),W_-1), x1c = min(max(x1,0),W_-1);
    const float v00 = xc[y0c*W_+x0c] * (my0*mx0);
    const float v01 = xc[y0c*W_+x1c] * (my0*mx1);
    const float v10 = xc[y1c*W_+x0c] * (my1*mx0);
    const float v11 = xc[y1c*W_+x1c] * (my1*mx1);
    return (v00*(1.f-ax) + v01*ax)*(1.f-ay) + (v10*(1.f-ax) + v11*ax)*ay;
}

// ---------------------------------------------------------------------------
// Fused: deformable conv (both dk) + 2-way softmax attention + weighted sum.
// Block = 64 consecutive pixels (one row segment) x all 64 output channels.
// Each thread: 4 px x 4 co register tile.
// ---------------------------------------------------------------------------
__global__ __launch_bounds__(256)
void deform_att_k(const float* __restrict__ x, const float* __restrict__ off,
                  const float* __restrict__ att, const float* __restrict__ wd,
                  float* __restrict__ out)
{
    __shared__ __align__(16) float offL[18][64];
    __shared__ __align__(16) float samp[8][9][64];   // [c_local][k][px]
    __shared__ __align__(16) float wdL [8][9][64];   // [c_local][k][o]
    const int tid = threadIdx.x;
    const int b   = blockIdx.z;
    const int oh  = blockIdx.y;
    const int ow0 = blockIdx.x * 64;
    const int px0 = (tid & 15) * 4;
    const int o0  = (tid >> 4) * 4;
    const float* xb = x + (size_t)b*C_*HW_;

    float outa[4][4];
#pragma unroll
    for (int i=0;i<4;i++)
#pragma unroll
        for (int j=0;j<4;j++) outa[i][j] = 0.f;

    for (int dk=0; dk<2; ++dk){
        __syncthreads();
        // stage offsets for this dk: 18 channels x 64 px
        for (int idx=tid; idx<18*64; idx+=256){
            const int cc = idx >> 6, px = idx & 63;
            offL[cc][px] = off[(((size_t)b*36 + dk*18 + cc)*H_ + oh)*W_ + ow0 + px];
        }
        float acc[4][4];
#pragma unroll
        for (int i=0;i<4;i++)
#pragma unroll
            for (int j=0;j<4;j++) acc[i][j] = 0.f;

        for (int c8=0; c8<8; ++c8){
            __syncthreads();   // prev einsum done; also makes offL visible on c8==0
            // stage wd chunk transposed: wdL[cl][k][o]
            for (int idx=tid; idx<8*9*64; idx+=256){
                const int o = idx/72, rem = idx - o*72;
                const int cl = rem/9, k = rem - cl*9;
                wdL[cl][k][o] = wd[((size_t)dk*64 + o)*576 + (size_t)(c8*8+cl)*9 + k];
            }
            // stage sampled tile: samp[cl][k][px]
            for (int idx=tid; idx<8*9*64; idx+=256){
                const int cl = idx/576, rem = idx - cl*576;
                const int k = rem >> 6, px = rem & 63;
                const float oy = offL[2*k  ][px];
                const float ox = offL[2*k+1][px];
                const float py  = (float)(oh  - 1 + (k/3)) + oy;
                const float pxx = (float)(ow0 + px - 1 + (k - (k/3)*3)) + ox;
                const float* xc = xb + (size_t)(c8*8+cl)*HW_;
                samp[cl][k][px] = bilin(xc, py, pxx);
            }
            __syncthreads();
            // einsum partial: 4px x 4o per thread
#pragma unroll
            for (int cl=0; cl<8; ++cl){
#pragma unroll
                for (int k=0; k<9; ++k){
                    const float4 s4 = *(const float4*)&samp[cl][k][px0];
                    const float4 w4 = *(const float4*)&wdL [cl][k][o0];
                    const float s[4] = {s4.x, s4.y, s4.z, s4.w};
                    const float wv[4] = {w4.x, w4.y, w4.z, w4.w};
#pragma unroll
                    for (int i=0;i<4;i++)
#pragma unroll
                        for (int j=0;j<4;j++)
                            acc[i][j] = fmaf(s[i], wv[j], acc[i][j]);
                }
            }
        }
        // softmax attention factor + accumulate into output accumulator
#pragma unroll
        for (int j=0;j<4;j++){
            const int o = o0 + j;
            const float4 as4 = *(const float4*)&att[(((size_t)b*128 + dk*64     + o)*H_ + oh)*W_ + ow0 + px0];
            const float4 ao4 = *(const float4*)&att[(((size_t)b*128 + (1-dk)*64 + o)*H_ + oh)*W_ + ow0 + px0];
            const float as[4] = {as4.x, as4.y, as4.z, as4.w};
            const float ao[4] = {ao4.x, ao4.y, ao4.z, ao4.w};
#pragma unroll
            for (int i=0;i<4;i++){
                const float f = 1.f / (1.f + __expf(ao[i] - as[i]));
                outa[i][j] = fmaf(acc[i][j], f, outa[i][j]);
            }
        }
    }
    // write output: 4 co rows x 4 consecutive px
#pragma unroll
    for (int j=0;j<4;j++){
        const float4 v = make_float4(outa[0][j], outa[1][j], outa[2][j], outa[3][j]);
        *(float4*)&out[(((size_t)b*64 + (o0+j))*H_ + oh)*W_ + ow0 + px0] = v;
    }
}

// ---------------------------------------------------------------------------
extern "C" void kernel_launch(void* const* d_in, const int* in_sizes, int n_in,
                              void* d_out, int out_size, void* d_ws, size_t ws_size,
                              hipStream_t stream)
{
    const float* x  = (const float*)d_in[0];
    const float* w1 = (const float*)d_in[1];
    const float* w2 = (const float*)d_in[2];
    const float* w3 = (const float*)d_in[3];
    const float* wa = (const float*)d_in[4];
    const float* wd = (const float*)d_in[5];
    float* out = (float*)d_out;

    float* ws   = (float*)d_ws;
    float* m1   = ws;                 // 8*64*128*128 = 8388608 floats
    float* m2   = m1 + 8388608;       // 8388608 floats
    float* offs = m2 + 8388608;       // 8*36*128*128 = 4718592 floats
    float* att  = m1;                 // reuse m1+m2 region: 16777216 floats
                                      // total ws use: 86 MB

    const dim3 blk(256);
    // m1 = relu(conv(x, w1))
    conv3x3_k<64, 64, 32, true ><<<dim3(64, 2, 8), blk, 0, stream>>>(x,  w1, m1);
    // m2 = relu(conv(m1, w2))
    conv3x3_k<64, 64, 32, true ><<<dim3(64, 2, 8), blk, 0, stream>>>(m1, w2, m2);
    // offsets = conv(m2, w3)
    conv3x3_k<64, 36, 36, false><<<dim3(64, 1, 8), blk, 0, stream>>>(m2, w3, offs);
    // att = conv(x, wa)   (overwrites m1/m2 region -- both already consumed)
    conv3x3_k<64,128, 32, false><<<dim3(64, 4, 8), blk, 0, stream>>>(x,  wa, att);
    // fused deform conv + softmax attention + weighted sum
    deform_att_k<<<dim3(2, 128, 8), blk, 0, stream>>>(x, offs, att, wd, out);
}